// Round 6
// baseline (1059.362 us; speedup 1.0000x reference)
//
#include <hip/hip_runtime.h>

#define LOG2E 1.4426950408889634f

constexpr int D      = 2048;
constexpr int NB     = 16;       // train buffer rows
constexpr int TPB    = 512;      // threads per block (8 waves)
constexpr int RPW    = 4;        // rows per wave
constexpr int NROWS  = 16384;    // B*T
constexpr int NBLK   = NROWS / (8 * RPW);   // 512 blocks -> 2 resident/CU

typedef float vfloat4 __attribute__((ext_vector_type(4)));

__device__ __forceinline__ float gelu_tanh_f(float x) {
    const float C = 0.7978845608028654f;   // sqrt(2/pi)
    const float K = 0.044715f;
    float x2 = x * x;
    float p  = __builtin_fmaf(K, x2, 1.0f);
    float z  = C * x * p;                   // c*(x + K x^3)
    float e  = __builtin_amdgcn_exp2f(z * (2.0f * LOG2E));
    float th = 1.0f - 2.0f * __builtin_amdgcn_rcpf(e + 1.0f);
    float hx = 0.5f * x;
    return __builtin_fmaf(hx, th, hx);      // 0.5x(1+tanh)
}

// round-to-nearest-even f32->bf16, packed pair (a=lo16, b=hi16)
__device__ __forceinline__ unsigned bpack(float a, float b) {
    unsigned ua = __builtin_bit_cast(unsigned, a);
    unsigned ub = __builtin_bit_cast(unsigned, b);
    ua += 0x7FFFu + ((ua >> 16) & 1u);
    ub += 0x7FFFu + ((ub >> 16) & 1u);
    return (ua >> 16) | (ub & 0xFFFF0000u);
}

__device__ __forceinline__ float blo(unsigned w) {
    return __builtin_bit_cast(float, w << 16);
}
__device__ __forceinline__ float bhi(unsigned w) {
    return __builtin_bit_cast(float, w & 0xFFFF0000u);
}

__global__ __launch_bounds__(TPB, 4) void gelu_gate_kernel(
    const float* __restrict__ x,
    const float* __restrict__ buf,
    const int* __restrict__ mask_i,
    const unsigned char* __restrict__ mask_b,
    const float* __restrict__ p_log_tau,
    const float* __restrict__ p_log_blend,
    float* __restrict__ out)
{
    // bf16 train buffer: 16 dots x 2048 elems x 2B = 64 KiB exactly.
    // Layout: quad (16B = 8 bf16) for (k, lane l, q) at byte
    //   k*4096 + l*64 + (q ^ ((l>>1)&3))*16
    // XOR swizzle gives 8 distinct bank-starts across lanes -> conflict-free
    // ds_read_b128 (64-B lane blocks without swizzle = 32-way conflict).
    __shared__ unsigned lds[NB * 1024];

    const int t    = threadIdx.x;
    const int lane = t & 63;
    const int wave = t >> 6;

    const float tau   = __builtin_amdgcn_exp2f(p_log_tau[0] * LOG2E);
    const float lbt   = p_log_blend[0];
    const float alpha = __builtin_amdgcn_rcpf(1.0f + __builtin_amdgcn_exp2f(-lbt * LOG2E));

    // bool dtype layout ambiguous (u8 vs i32) -> accept either (all-true dataset)
    unsigned mbits = 0;
#pragma unroll
    for (int k = 0; k < NB; ++k) {
        bool mk = (mask_i[k] != 0) || (mask_b[k] != 0);
        mbits |= (mk ? 1u : 0u) << k;
    }

    // ---- stage buf -> LDS (bf16, swizzled), once per block ----
    {
        const float4* buf4 = reinterpret_cast<const float4*>(buf);
        char* ldsb = reinterpret_cast<char*>(lds);
#pragma unroll
        for (int i = 0; i < 8; ++i) {
            const int g = t + TPB * i;          // global quad id (8 elems each)
            const int k = g >> 8;
            const int m = g & 255;              // quad within row
            const int l = m >> 2;
            const int q = m & 3;
            float4 a = buf4[g * 2 + 0];
            float4 b = buf4[g * 2 + 1];
            uint4 w;
            w.x = bpack(a.x, a.y);
            w.y = bpack(a.z, a.w);
            w.z = bpack(b.x, b.y);
            w.w = bpack(b.z, b.w);
            const int pq = q ^ ((l >> 1) & 3);
            *reinterpret_cast<uint4*>(ldsb + k * 4096 + l * 64 + pq * 16) = w;
        }
    }
    __syncthreads();   // the ONLY barrier; waves are independent after this

    // per-lane swizzled read bases (byte offsets), k added as imm offset
    const char* ldsb = reinterpret_cast<const char*>(lds);
    int vq[4];
#pragma unroll
    for (int q = 0; q < 4; ++q)
        vq[q] = lane * 64 + ((q ^ ((lane >> 1) & 3)) * 16);

    const float4* x4   = reinterpret_cast<const float4*>(x);
    vfloat4*      out4 = reinterpret_cast<vfloat4*>(out);

    const bool b5 = lane & 32;
    const bool b4 = lane & 16;
    const bool b3 = lane & 8;
    const bool b2 = lane & 4;
    const int  kk = (lane >> 2) & 15;   // dot this lane owns post-reduction

    const int wgid = blockIdx.x * 8 + wave;

    for (int r = 0; r < RPW; ++r) {
        const int row = wgid * RPW + r;
        const size_t base = (size_t)row * (D / 4) + lane * 8;

        // lane owns elements [32*lane, 32*lane+32): 8 contiguous float4
        float y[32];
#pragma unroll
        for (int u = 0; u < 8; ++u) {
            float4 v = x4[base + u];
            y[4 * u + 0] = v.x;
            y[4 * u + 1] = v.y;
            y[4 * u + 2] = v.z;
            y[4 * u + 3] = v.w;
        }
#pragma unroll
        for (int i = 0; i < 32; ++i) y[i] = gelu_tanh_f(y[i]);

        float s2 = 0.f;
#pragma unroll
        for (int i = 0; i < 32; ++i) s2 = __builtin_fmaf(y[i], y[i], s2);

        // 16 dots, B-operand from swizzled LDS (4x ds_read_b128 per dot,
        // compile-time offset k*4096 <= 61440 fits the 16-bit DS imm)
        float d[NB];
#pragma unroll
        for (int k = 0; k < NB; ++k) {
            uint4 w[4];
#pragma unroll
            for (int q = 0; q < 4; ++q)
                w[q] = *reinterpret_cast<const uint4*>(ldsb + vq[q] + k * 4096);
            float dk = 0.f;
#pragma unroll
            for (int q = 0; q < 4; ++q) {
                const unsigned ww[4] = { w[q].x, w[q].y, w[q].z, w[q].w };
#pragma unroll
                for (int c = 0; c < 4; ++c) {
                    const int e = 8 * q + 2 * c;
                    dk = __builtin_fmaf(y[e + 0], blo(ww[c]), dk);
                    dk = __builtin_fmaf(y[e + 1], bhi(ww[c]), dk);
                }
            }
            d[k] = dk;
        }

        // ---- wave-local value-halving reduction (27 shfls total) ----
        float e8[8];
#pragma unroll
        for (int i = 0; i < 8; ++i) {
            float mine  = b5 ? d[i + 8] : d[i];
            float other = b5 ? d[i]     : d[i + 8];
            e8[i] = mine + __shfl_xor(other, 32, 64);
        }
        float e4[4];
#pragma unroll
        for (int i = 0; i < 4; ++i) {
            float mine  = b4 ? e8[i + 4] : e8[i];
            float other = b4 ? e8[i]     : e8[i + 4];
            e4[i] = mine + __shfl_xor(other, 16, 64);
        }
        float e2[2];
#pragma unroll
        for (int i = 0; i < 2; ++i) {
            float mine  = b3 ? e4[i + 2] : e4[i];
            float other = b3 ? e4[i]     : e4[i + 2];
            e2[i] = mine + __shfl_xor(other, 8, 64);
        }
        float e1;
        {
            float mine  = b2 ? e2[1] : e2[0];
            float other = b2 ? e2[0] : e2[1];
            e1 = mine + __shfl_xor(other, 4, 64);
        }
        e1 += __shfl_xor(e1, 2, 64);
        e1 += __shfl_xor(e1, 1, 64);   // lane holds full dot kk

        // ||y||^2 butterfly
#pragma unroll
        for (int off = 32; off >= 1; off >>= 1)
            s2 += __shfl_xor(s2, off, 64);

        const float inv = __builtin_amdgcn_rcpf(fmaxf(__builtin_sqrtf(s2), 1e-12f));
        float sim = e1 * inv;
        if (!((mbits >> kk) & 1u)) sim = -1.0f;
        // max over the 16 dots (xor bits 2..5); every lane gets the max
        sim = fmaxf(sim, __shfl_xor(sim, 4, 64));
        sim = fmaxf(sim, __shfl_xor(sim, 8, 64));
        sim = fmaxf(sim, __shfl_xor(sim, 16, 64));
        sim = fmaxf(sim, __shfl_xor(sim, 32, 64));

        const float g    = __builtin_amdgcn_exp2f(-tau * sim * LOG2E);
        const float gate = __builtin_fmaf(alpha, g, 1.0f - alpha);

#pragma unroll
        for (int u = 0; u < 8; ++u) {
            vfloat4 o;
            o.x = y[4 * u + 0] * gate;
            o.y = y[4 * u + 1] * gate;
            o.z = y[4 * u + 2] * gate;
            o.w = y[4 * u + 3] * gate;
            __builtin_nontemporal_store(o, &out4[base + u]);
        }
    }
}

extern "C" void kernel_launch(void* const* d_in, const int* in_sizes, int n_in,
                              void* d_out, int out_size, void* d_ws, size_t ws_size,
                              hipStream_t stream) {
    const float*         x      = (const float*)d_in[0];
    const float*         buf    = (const float*)d_in[1];
    const int*           mask_i = (const int*)d_in[2];
    const unsigned char* mask_b = (const unsigned char*)d_in[2];
    const float*         lt     = (const float*)d_in[3];
    const float*         lb     = (const float*)d_in[4];
    float*               out    = (float*)d_out;

    gelu_gate_kernel<<<NBLK, TPB, 0, stream>>>(x, buf, mask_i, mask_b, lt, lb, out);
}

// Round 7
// 78.722 us; speedup vs baseline: 13.4569x; 13.4569x over previous
//
#include <hip/hip_runtime.h>

#define LOG2E 1.4426950408889634f

constexpr int D     = 2048;
constexpr int NB    = 16;       // train buffer rows (= MFMA N)
constexpr int TPB   = 512;      // 8 waves: 2 row-groups x 4 k-waves
constexpr int NROWS = 16384;    // B*T
constexpr int RPB   = 32;       // rows per block (2 groups x 16)
constexpr int NBLK  = NROWS / RPB;   // 512 blocks -> exactly 2/CU

typedef short bf16x8 __attribute__((ext_vector_type(8)));
typedef float f32x4  __attribute__((ext_vector_type(4)));

__device__ __forceinline__ float gelu_tanh_f(float x) {
    const float C = 0.7978845608028654f;   // sqrt(2/pi)
    const float K = 0.044715f;
    float x2 = x * x;
    float p  = __builtin_fmaf(K, x2, 1.0f);
    float z  = C * x * p;                   // c*(x + K x^3)
    float e  = __builtin_amdgcn_exp2f(z * (2.0f * LOG2E));
    float th = 1.0f - 2.0f * __builtin_amdgcn_rcpf(e + 1.0f);
    float hx = 0.5f * x;
    return __builtin_fmaf(hx, th, hx);      // 0.5x(1+tanh)
}

// round-to-nearest-even f32->bf16, packed pair (a=low16, b=high16)
__device__ __forceinline__ unsigned bpack(float a, float b) {
    unsigned ua = __builtin_bit_cast(unsigned, a);
    unsigned ub = __builtin_bit_cast(unsigned, b);
    ua += 0x7FFFu + ((ua >> 16) & 1u);
    ub += 0x7FFFu + ((ub >> 16) & 1u);
    return (ua >> 16) | (ub & 0xFFFF0000u);
}
__device__ __forceinline__ float blo(unsigned w) {
    return __builtin_bit_cast(float, w << 16);
}
__device__ __forceinline__ float bhi(unsigned w) {
    return __builtin_bit_cast(float, w & 0xFFFF0000u);
}

__global__ void __launch_bounds__(TPB)
__attribute__((amdgpu_waves_per_eu(4, 4)))   // pin 4 waves/EU -> 128-VGPR budget
gelu_gate_kernel(
    const float* __restrict__ x,
    const float* __restrict__ buf,
    const int* __restrict__ mask_i,
    const unsigned char* __restrict__ mask_b,
    const float* __restrict__ p_log_tau,
    const float* __restrict__ p_log_blend,
    float* __restrict__ out)
{
    // B-fragments, bf16: dword id -> (kt_global = id>>8) * 256 + lane*4 + jw
    // element: n = (id>>2)&15, k = (id>>8)*32 + ((id>>6)&3)*8 + (id&3)*2 (+pair)
    __shared__ unsigned ldsB[NB * 1024];     // 64 KiB
    __shared__ f32x4    ldsAcc[8][64];       // 8 KiB  cross-wave dot partials
    __shared__ float    ldsS2[8][16];        // 512 B  cross-wave ||y||^2

    const int t    = threadIdx.x;
    const int lane = t & 63;
    const int wave = t >> 6;
    const int g    = wave >> 2;   // row-group 0/1
    const int wk   = wave & 3;    // k-chunk 0..3

    const float tau   = __builtin_amdgcn_exp2f(p_log_tau[0] * LOG2E);
    const float lbt   = p_log_blend[0];
    const float alpha = __builtin_amdgcn_rcpf(1.0f + __builtin_amdgcn_exp2f(-lbt * LOG2E));

    // bool dtype layout ambiguous (u8 vs i32) -> accept either (all-true dataset)
    unsigned mbits = 0;
#pragma unroll
    for (int k = 0; k < NB; ++k) {
        bool mk = (mask_i[k] != 0) || (mask_b[k] != 0);
        mbits |= (mk ? 1u : 0u) << k;
    }

    // ---- stage buf -> LDS as MFMA B-fragments (bf16), once per block ----
#pragma unroll
    for (int i = 0; i < 32; ++i) {
        const int id = t + TPB * i;
        const int n  = (id >> 2) & 15;
        const int k  = ((id >> 8) << 5) + (((id >> 6) & 3) << 3) + ((id & 3) << 1);
        const float* p = buf + n * D + k;
        ldsB[id] = bpack(p[0], p[1]);
    }
    __syncthreads();

    const int m     = lane & 15;        // A row within group / C col n
    const int kgrp  = lane >> 4;        // 0..3
    const int row   = blockIdx.x * RPB + g * 16 + m;
    const int kbase = wk * 512 + kgrp * 8;
    const float* xp = x   + (size_t)row * D + kbase;
    float*       op = out + (size_t)row * D + kbase;
    const unsigned* Bb = ldsB + wk * 16 * 256 + lane * 4;

    // ---- pass 1: gelu + s2 + MFMA dot accumulation over 16 k-tiles ----
    f32x4 acc = {0.f, 0.f, 0.f, 0.f};
    float s2 = 0.f;
    uint4 ypk[16];                       // packed bf16 y, 64 VGPRs

#pragma unroll
    for (int kt = 0; kt < 16; ++kt) {
        float4 a = *reinterpret_cast<const float4*>(xp + kt * 32);
        float4 b = *reinterpret_cast<const float4*>(xp + kt * 32 + 4);
        float y0 = gelu_tanh_f(a.x), y1 = gelu_tanh_f(a.y);
        float y2 = gelu_tanh_f(a.z), y3 = gelu_tanh_f(a.w);
        float y4 = gelu_tanh_f(b.x), y5 = gelu_tanh_f(b.y);
        float y6 = gelu_tanh_f(b.z), y7 = gelu_tanh_f(b.w);
        s2 = __builtin_fmaf(y0, y0, s2); s2 = __builtin_fmaf(y1, y1, s2);
        s2 = __builtin_fmaf(y2, y2, s2); s2 = __builtin_fmaf(y3, y3, s2);
        s2 = __builtin_fmaf(y4, y4, s2); s2 = __builtin_fmaf(y5, y5, s2);
        s2 = __builtin_fmaf(y6, y6, s2); s2 = __builtin_fmaf(y7, y7, s2);
        uint4 yp;
        yp.x = bpack(y0, y1); yp.y = bpack(y2, y3);
        yp.z = bpack(y4, y5); yp.w = bpack(y6, y7);
        ypk[kt] = yp;
        const uint4 bq = *reinterpret_cast<const uint4*>(Bb + kt * 256);
        acc = __builtin_amdgcn_mfma_f32_16x16x32_bf16(
            __builtin_bit_cast(bf16x8, yp), __builtin_bit_cast(bf16x8, bq),
            acc, 0, 0, 0);
        if ((kt & 3) == 3) __builtin_amdgcn_sched_barrier(0);  // cap load hoisting
    }

    // in-wave s2: sum the 4 k-groups -> every lane holds s2 of row m (this wave's k-chunk)
    s2 += __shfl_xor(s2, 16, 64);
    s2 += __shfl_xor(s2, 32, 64);

    ldsAcc[g * 4 + wk][lane] = acc;
    if (lane < 16) ldsS2[g * 4 + wk][lane] = s2;
    __syncthreads();

    // ---- combine across the group's 4 k-waves (redundant in each wave) ----
    f32x4 dt = ldsAcc[g * 4 + 0][lane];
    dt += ldsAcc[g * 4 + 1][lane];
    dt += ldsAcc[g * 4 + 2][lane];
    dt += ldsAcc[g * 4 + 3][lane];

    float gate[4];
#pragma unroll
    for (int j = 0; j < 4; ++j) {
        const int r = kgrp * 4 + j;          // C row = x-row for this reg
        const float s2t = ldsS2[g * 4 + 0][r] + ldsS2[g * 4 + 1][r] +
                          ldsS2[g * 4 + 2][r] + ldsS2[g * 4 + 3][r];
        const float inv = __builtin_amdgcn_rcpf(fmaxf(__builtin_sqrtf(s2t), 1e-12f));
        float s = dt[j] * inv;               // sim of row r with buf n = m
        if (!((mbits >> m) & 1u)) s = -1.0f;
        s = fmaxf(s, __shfl_xor(s, 1, 64));  // max over n (lane bits 0-3)
        s = fmaxf(s, __shfl_xor(s, 2, 64));
        s = fmaxf(s, __shfl_xor(s, 4, 64));
        s = fmaxf(s, __shfl_xor(s, 8, 64));
        gate[j] = __builtin_fmaf(alpha, __builtin_amdgcn_exp2f(-tau * s * LOG2E),
                                 1.0f - alpha);
    }
    // redistribute: lane needs gate of row m -> held as reg (m&3) of lane (m>>2)<<4
    const int src = (lane & 12) << 2;
    const float g0 = __shfl(gate[0], src, 64);
    const float g1 = __shfl(gate[1], src, 64);
    const float g2 = __shfl(gate[2], src, 64);
    const float g3 = __shfl(gate[3], src, 64);
    const float gm = (lane & 2) ? ((lane & 1) ? g3 : g2)
                                : ((lane & 1) ? g1 : g0);

    // ---- pass 2: unpack y, scale, store ----
#pragma unroll
    for (int kt = 0; kt < 16; ++kt) {
        const uint4 w = ypk[kt];
        float4 o1, o2;
        o1.x = blo(w.x) * gm; o1.y = bhi(w.x) * gm;
        o1.z = blo(w.y) * gm; o1.w = bhi(w.y) * gm;
        o2.x = blo(w.z) * gm; o2.y = bhi(w.z) * gm;
        o2.z = blo(w.w) * gm; o2.w = bhi(w.w) * gm;
        *reinterpret_cast<float4*>(op + kt * 32)     = o1;
        *reinterpret_cast<float4*>(op + kt * 32 + 4) = o2;
    }
}

extern "C" void kernel_launch(void* const* d_in, const int* in_sizes, int n_in,
                              void* d_out, int out_size, void* d_ws, size_t ws_size,
                              hipStream_t stream) {
    const float*         x      = (const float*)d_in[0];
    const float*         buf    = (const float*)d_in[1];
    const int*           mask_i = (const int*)d_in[2];
    const unsigned char* mask_b = (const unsigned char*)d_in[2];
    const float*         lt     = (const float*)d_in[3];
    const float*         lb     = (const float*)d_in[4];
    float*               out    = (float*)d_out;

    gelu_gate_kernel<<<NBLK, TPB, 0, stream>>>(x, buf, mask_i, mask_b, lt, lb, out);
}